// Round 3
// baseline (434.642 us; speedup 1.0000x reference)
//
#include <hip/hip_runtime.h>
#include <hip/hip_bf16.h>
#include <math.h>

// SelfAttentionLayer: B=8,S=2048,D=1024 (fp32 interface).
// R7: pipeline deepening at constant LDS. R6 counters: MfmaUtil 22%, LDS port
//   ~34%, HBM 23%, all low -> latency/serialization-bound: depth-1 prefetch +
//   vmcnt(0)+barrier per iter exposes loaded-HBM latency (~1200cy) vs ~750cy
//   of per-iter work. Residual SQ_LDS_BANK_CONFLICT = exactly 4cy/ds_read_b128
//   (structural b128 cost, m134) -> LDS reads already optimal.
//   Fix: 4 stages x BK=64 (16KB/stage, same 64KB, 2 blocks/CU), DEPTH-2
//   prefetch with counted vmcnt(8) (T3/T4: never drain to 0 until tail) ->
//   each stage gets 2 full iterations of load latency budget. One raw
//   s_barrier/iter; buffer-reuse hazard covered by the one-stage slack (stage
//   it rewritten at iter it+2, after iter it+1's top barrier). T5 setprio(1)
//   around the 4-MFMA cluster.
//   BK=64 = 64B rows can't cover 32 banks -> paired-row layout: 128B LDS line
//   r holds rows {r, r+64} (chunks 0-3 / 4-7), slot = chunk ^ (line&7) ->
//   8 dwords/bank per b128 (optimal, verified by construction both sides).
// Numerics identical to R5/R6: MX-fp8 e4m3 unit scales, P x256, AO x16,
//   residual+LN fp32, preLN bf16. Kept: XCD chunk swizzle.

typedef __bf16 bf16;
typedef unsigned char u8;
typedef __attribute__((ext_vector_type(8))) __bf16 bf16x8;
typedef __attribute__((ext_vector_type(4))) __bf16 bf16x4;
typedef __attribute__((ext_vector_type(8))) int i32x8;
typedef __attribute__((ext_vector_type(16))) float f32x16;

__device__ __forceinline__ void async16(const u8* g, u8* l) {
    __builtin_amdgcn_global_load_lds(
        (const __attribute__((address_space(1))) void*)g,
        (__attribute__((address_space(3))) void*)l, 16, 0, 0);
}

// s_waitcnt imm: bits[3:0] vmcnt, [6:4] expcnt, [11:8] lgkmcnt
#define WAITCNT_VM(n) __builtin_amdgcn_s_waitcnt((15 << 8) | (7 << 4) | (n))

__device__ __forceinline__ u8 to_fp8(float v) {
    return (u8)(__builtin_amdgcn_cvt_pk_fp8_f32(v, v, 0, 0) & 0xFF);
}

__global__ __launch_bounds__(256) void cast_f32_fp8(
    const float* __restrict__ in, u8* __restrict__ out, int n)
{
    int i = (blockIdx.x * 256 + threadIdx.x) * 8;
    if (i >= n) return;
    float4 a = *(const float4*)(in + i);
    float4 b = *(const float4*)(in + i + 4);
    int lo = __builtin_amdgcn_cvt_pk_fp8_f32(a.x, a.y, 0, 0);
    lo = __builtin_amdgcn_cvt_pk_fp8_f32(a.z, a.w, lo, 1);
    int hi = __builtin_amdgcn_cvt_pk_fp8_f32(b.x, b.y, 0, 0);
    hi = __builtin_amdgcn_cvt_pk_fp8_f32(b.z, b.w, hi, 1);
    int2 o = { lo, hi };
    *(int2*)(out + i) = o;
}

// C[m,n] = scale * sum_k A[m,k]*B[n,k] (+bias); A:[M,K] lda, B:[N,K] ldb, fp8.
// bias_mode: 0 none, 1 bias[n], 2 bias[m]. c_mode: 0 bf16 out, 1 fp8 out.
// grid (N/128, M/128, batch), 256 thr = 4 waves, wave=64x64 (2x2 of 32x32x64).
// K must be a multiple of 128 (iters = K/64 >= 2).
__global__ __launch_bounds__(256) void gemm_f8(
    const u8* __restrict__ A, long lda, long sA,
    const u8* __restrict__ B, long ldb, long sB,
    void* __restrict__ Cv, long ldc, long sC,
    const float* __restrict__ bias, int bias_mode,
    float scale, int c_mode, int K)
{
    // 4 stages x 16KB. Stage: A 8KB (64 lines x 128B) | B 8KB.
    // Line r holds rows {r, r+64}: chunks 0-3 = row r k-bytes [0,64),
    // chunks 4-7 = row r+64. Slot for (line, chunk): pos = chunk ^ (line&7).
    __shared__ u8 lds[4][16384];

    // XCD chunk swizzle: flat%8 is the XCD round-robin -> give each XCD a
    // contiguous flat range for L2 tile reuse.
    const int gx = gridDim.x, gy = gridDim.y;
    const int slice = gx * gy;
    const int total = slice * gridDim.z;
    int flat = ((int)blockIdx.z * gy + (int)blockIdx.y) * gx + (int)blockIdx.x;
    if ((total & 7) == 0)
        flat = (flat & 7) * (total >> 3) + (flat >> 3);
    const int bz = flat / slice;
    const int rem = flat - bz * slice;
    const int by = rem / gx;
    const int bx = rem - by * gx;

    const int tid = threadIdx.x;
    const long tM = (long)by * 128;
    const long tN = (long)bx * 128;
    A += (long)bz * sA;
    B += (long)bz * sB;

    // staging: thread tid -> slot (line = tid>>3, pos = tid&7) and the
    // +32-line slot. chunk = pos ^ (line&7) ((line+32)&7 == line&7 -> same
    // chunk for both). Global source: row = line + (chunk>=4)*64 (+32 for
    // slot1), k-byte = (chunk&3)*16. LDS dest lane-linear tid*16 (required
    // by global_load_lds). Per 8 threads: one line = two 64B row-segments.
    const int sline = tid >> 3;                   // 0..31
    const int sch = (tid & 7) ^ (sline & 7);
    const int skb = (sch & 3) << 4;               // k-byte within 64B
    const int srofs = (sch & 4) << 4;             // +64 rows if chunk >= 4
    const u8* gA0 = A + (tM + sline + srofs) * lda + skb;   // lines 0..31
    const u8* gA1 = gA0 + 32 * lda;                          // lines 32..63
    const u8* gB0 = B + (tN + sline + srofs) * ldb + skb;
    const u8* gB1 = gB0 + 32 * ldb;
    const int dA0 = tid * 16,        dA1 = 4096 + tid * 16;
    const int dB0 = 8192 + tid * 16, dB1 = 12288 + tid * 16;

    const int w = tid >> 6, lane = tid & 63;
    const int wm = (w & 1) * 64, wn = (w >> 1) * 64;
    const int r32 = lane & 31, kh = lane >> 5;   // kh: which 32-byte K-half

    f32x16 acc[2][2] = {};

    const int iters = K >> 6;

    // prologue: stages 0,1 (depth-2)
    {
        u8* p = lds[0];
        async16(gA0, p + dA0); async16(gA1, p + dA1);
        async16(gB0, p + dB0); async16(gB1, p + dB1);
        u8* q = lds[1];
        async16(gA0 + 64, q + dA0); async16(gA1 + 64, q + dA1);
        async16(gB0 + 64, q + dB0); async16(gB1 + 64, q + dB1);
    }

    // fragment read offsets. Frag rows wm+r32 / wm+32+r32 -> lines r32 /
    // 32+r32 (same line&7), chunk base cb = 4 if wm==64 (rows >= 64 live in
    // the high chunk half), k-half kh picks chunks cb+2kh+{0,1}.
    const int xr = r32 & 7;
    const int cbA = (w & 1) ? 4 : 0;
    const int cbB = (w >> 1) ? 4 : 0;
    const int oA0q0 = r32 * 128 + (((cbA + (kh << 1) + 0) ^ xr) << 4);
    const int oA0q1 = r32 * 128 + (((cbA + (kh << 1) + 1) ^ xr) << 4);
    const int oB0q0 = 8192 + r32 * 128 + (((cbB + (kh << 1) + 0) ^ xr) << 4);
    const int oB0q1 = 8192 + r32 * 128 + (((cbB + (kh << 1) + 1) ^ xr) << 4);

    for (int it = 0; it < iters; ++it) {
        // depth-2 counted vmcnt (T3/T4): issue stage it+2 first, then wait
        // to 8 outstanding -> drains exactly stage it's 4 loads, keeps 8 in
        // flight across the barrier. Tail: 4, then 0.
        if (it + 2 < iters) {
            u8* p = lds[(it + 2) & 3];
            const long ko = (long)(it + 2) << 6;
            async16(gA0 + ko, p + dA0); async16(gA1 + ko, p + dA1);
            async16(gB0 + ko, p + dB0); async16(gB1 + ko, p + dB1);
            WAITCNT_VM(8);
        } else if (it + 1 < iters) {
            WAITCNT_VM(4);
        } else {
            WAITCNT_VM(0);
        }
        __builtin_amdgcn_s_barrier();
        // buffer-reuse hazard: stage it's buffer is rewritten by the issue at
        // iter it+2, which every wave reaches only after iter it+1's barrier,
        // by which point all waves' iter-it ds_reads are register-consumed.

        const u8* cb = lds[it & 3];
        union F { i32x8 v; int4 q[2]; };
        F a0, a1, b0, b1;
        a0.q[0] = *(const int4*)&cb[oA0q0];
        a0.q[1] = *(const int4*)&cb[oA0q1];
        a1.q[0] = *(const int4*)&cb[oA0q0 + 4096];
        a1.q[1] = *(const int4*)&cb[oA0q1 + 4096];
        b0.q[0] = *(const int4*)&cb[oB0q0];
        b0.q[1] = *(const int4*)&cb[oB0q1];
        b1.q[0] = *(const int4*)&cb[oB0q0 + 4096];
        b1.q[1] = *(const int4*)&cb[oB0q1 + 4096];

        // fmt 0 = OCP fp8 e4m3; scales 0x7F (=2^0) in every byte, opsel 0
        __builtin_amdgcn_s_setprio(1);
        acc[0][0] = __builtin_amdgcn_mfma_scale_f32_32x32x64_f8f6f4(
            a0.v, b0.v, acc[0][0], 0, 0, 0, 0x7F7F7F7F, 0, 0x7F7F7F7F);
        acc[0][1] = __builtin_amdgcn_mfma_scale_f32_32x32x64_f8f6f4(
            a0.v, b1.v, acc[0][1], 0, 0, 0, 0x7F7F7F7F, 0, 0x7F7F7F7F);
        acc[1][0] = __builtin_amdgcn_mfma_scale_f32_32x32x64_f8f6f4(
            a1.v, b0.v, acc[1][0], 0, 0, 0, 0x7F7F7F7F, 0, 0x7F7F7F7F);
        acc[1][1] = __builtin_amdgcn_mfma_scale_f32_32x32x64_f8f6f4(
            a1.v, b1.v, acc[1][1], 0, 0, 0, 0x7F7F7F7F, 0, 0x7F7F7F7F);
        __builtin_amdgcn_s_setprio(0);
    }

    // epilogue: 32x32 C/D layout col=lane&31, row=(reg&3)+8*(reg>>2)+4*kh
    // [m74/m101; dtype-independent m121-128]
#pragma unroll
    for (int i = 0; i < 2; i++) {
#pragma unroll
        for (int j = 0; j < 2; j++) {
            const long gn = tN + wn + j * 32 + r32;
            const float bn = (bias_mode == 1) ? bias[gn] : 0.0f;
#pragma unroll
            for (int reg = 0; reg < 16; reg++) {
                const int rowf = (reg & 3) + 8 * (reg >> 2) + 4 * kh;
                const long gm = tM + wm + i * 32 + rowf;
                float v = acc[i][j][reg] * scale + bn;
                if (bias_mode == 2) v += bias[gm];
                if (c_mode == 0)
                    ((bf16*)Cv + (long)bz * sC)[gm * ldc + gn] = (bf16)v;
                else
                    ((u8*)Cv + (long)bz * sC)[gm * ldc + gn] = to_fp8(v);
            }
        }
    }
}

// softmax over rows of 2048 bf16 scores -> fp8 P scaled x256
__global__ __launch_bounds__(256) void softmax_f8(
    const bf16* __restrict__ S, u8* __restrict__ P)
{
    const long row = blockIdx.x;
    const bf16* p = S + row * 2048;
    const int t = threadIdx.x;

    bf16x8 v = *(const bf16x8*)(p + t * 8);
    float f[8];
    float m = -3.0e38f;
#pragma unroll
    for (int i = 0; i < 8; i++) { f[i] = (float)v[i]; m = fmaxf(m, f[i]); }
    for (int o = 32; o; o >>= 1) m = fmaxf(m, __shfl_down(m, o));

    __shared__ float sm[4], ssum[4];
    if ((t & 63) == 0) sm[t >> 6] = m;
    __syncthreads();
    m = fmaxf(fmaxf(sm[0], sm[1]), fmaxf(sm[2], sm[3]));

    float s = 0.0f;
#pragma unroll
    for (int i = 0; i < 8; i++) { f[i] = __expf(f[i] - m); s += f[i]; }
    for (int o = 32; o; o >>= 1) s += __shfl_down(s, o);
    if ((t & 63) == 0) ssum[t >> 6] = s;
    __syncthreads();
    s = ssum[0] + ssum[1] + ssum[2] + ssum[3];

    const float c = 256.0f / s;   // x256: keep P out of fp8 subnormal range
    int lo = __builtin_amdgcn_cvt_pk_fp8_f32(f[0] * c, f[1] * c, 0, 0);
    lo = __builtin_amdgcn_cvt_pk_fp8_f32(f[2] * c, f[3] * c, lo, 1);
    int hi = __builtin_amdgcn_cvt_pk_fp8_f32(f[4] * c, f[5] * c, 0, 0);
    hi = __builtin_amdgcn_cvt_pk_fp8_f32(f[6] * c, f[7] * c, hi, 1);
    int2 o = { lo, hi };
    *(int2*)(P + row * 2048 + t * 8) = o;
}

// out = LN(pre + x) * gamma + beta; pre bf16, x fp32; rows of 1024
__global__ __launch_bounds__(256) void ln_res(
    const bf16* __restrict__ pre, const float* __restrict__ x,
    const float* __restrict__ gamma, const float* __restrict__ beta,
    float* __restrict__ out)
{
    const long row = blockIdx.x;
    const int t = threadIdx.x;
    const long base = row * 1024 + t * 4;

    bf16x4 a = *(const bf16x4*)(pre + base);
    float4 b = *(const float4*)(x + base);
    float v0 = (float)a[0] + b.x, v1 = (float)a[1] + b.y;
    float v2 = (float)a[2] + b.z, v3 = (float)a[3] + b.w;

    float s = v0 + v1 + v2 + v3;
    float q = v0 * v0 + v1 * v1 + v2 * v2 + v3 * v3;
    for (int o = 32; o; o >>= 1) { s += __shfl_down(s, o); q += __shfl_down(q, o); }

    __shared__ float ls[4], lq[4];
    if ((t & 63) == 0) { ls[t >> 6] = s; lq[t >> 6] = q; }
    __syncthreads();
    s = ls[0] + ls[1] + ls[2] + ls[3];
    q = lq[0] + lq[1] + lq[2] + lq[3];

    const float mean = s * (1.0f / 1024.0f);
    const float var = q * (1.0f / 1024.0f) - mean * mean;
    const float rstd = rsqrtf(var + 1e-5f);

    const int c = t * 4;
    float4 g = *(const float4*)(gamma + c);
    float4 be = *(const float4*)(beta + c);
    float4 o;
    o.x = (v0 - mean) * rstd * g.x + be.x;
    o.y = (v1 - mean) * rstd * g.y + be.y;
    o.z = (v2 - mean) * rstd * g.z + be.z;
    o.w = (v3 - mean) * rstd * g.w + be.w;
    *(float4*)(out + base) = o;
}

extern "C" void kernel_launch(void* const* d_in, const int* in_sizes, int n_in,
                              void* d_out, int out_size, void* d_ws, size_t ws_size,
                              hipStream_t stream)
{
    const float* x     = (const float*)d_in[0];
    const float* Wq    = (const float*)d_in[1];
    const float* bq    = (const float*)d_in[2];
    const float* Wk    = (const float*)d_in[3];
    const float* bk    = (const float*)d_in[4];
    const float* Wv    = (const float*)d_in[5];
    const float* bv    = (const float*)d_in[6];
    const float* Wo    = (const float*)d_in[7];
    const float* bo    = (const float*)d_in[8];
    const float* gamma = (const float*)d_in[9];
    const float* beta  = (const float*)d_in[10];
    float* out = (float*)d_out;

    char* ws = (char*)d_ws;
    u8* x8  = (u8*)(ws + (size_t)0);          // 16 MB [16384,1024]
    u8* Q8  = (u8*)(ws + (size_t)16777216);   // 16 MB (reused as AO8)
    u8* K8  = (u8*)(ws + (size_t)33554432);   // 16 MB
    u8* VT8 = (u8*)(ws + (size_t)50331648);   // 16 MB [1024,16384]
    u8* P8  = (u8*)(ws + (size_t)67108864);   // 32 MB [8,2048,2048]
    bf16* Sb = (bf16*)(ws + (size_t)104857600); // 64 MB scores; preLN reuse
    u8* Wq8 = (u8*)(ws + (size_t)176160768);
    u8* Wk8 = Wq8 + 1048576;
    u8* Wv8 = Wk8 + 1048576;
    u8* Wo8 = Wv8 + 1048576;

    // casts
    cast_f32_fp8<<<8192, 256, 0, stream>>>(x, x8, 16777216);
    cast_f32_fp8<<<512, 256, 0, stream>>>(Wq, Wq8, 1048576);
    cast_f32_fp8<<<512, 256, 0, stream>>>(Wk, Wk8, 1048576);
    cast_f32_fp8<<<512, 256, 0, stream>>>(Wv, Wv8, 1048576);
    cast_f32_fp8<<<512, 256, 0, stream>>>(Wo, Wo8, 1048576);

    // Q8 = x8@Wq8^T + bq  (fp8 out)
    gemm_f8<<<dim3(8, 128, 1), 256, 0, stream>>>(
        x8, 1024, 0, Wq8, 1024, 0, (void*)Q8, 1024, 0, bq, 1, 1.0f, 1, 1024);
    // K8
    gemm_f8<<<dim3(8, 128, 1), 256, 0, stream>>>(
        x8, 1024, 0, Wk8, 1024, 0, (void*)K8, 1024, 0, bk, 1, 1.0f, 1, 1024);
    // VT8 = Wv8@x8^T + bv(row)  [1024,16384] fp8
    gemm_f8<<<dim3(128, 8, 1), 256, 0, stream>>>(
        Wv8, 1024, 0, x8, 1024, 0, (void*)VT8, 16384, 0, bv, 2, 1.0f, 1, 1024);
    // scores (bf16) = Q8@K8^T / 32, per batch
    gemm_f8<<<dim3(16, 16, 8), 256, 0, stream>>>(
        Q8, 1024, 2097152, K8, 1024, 2097152, (void*)Sb, 2048, 4194304,
        nullptr, 0, 0.03125f, 0, 1024);
    // P8 = softmax(scores) * 256  (fp8)
    softmax_f8<<<16384, 256, 0, stream>>>(Sb, P8);
    // AO8 = (P8@VT8^T) * 16/256  -> stored AO = 16*AO_true (into Q8)
    gemm_f8<<<dim3(8, 16, 8), 256, 0, stream>>>(
        P8, 2048, 4194304, VT8, 16384, 2048, (void*)Q8, 1024, 2097152,
        nullptr, 0, 0.0625f, 1, 2048);
    // preLN (bf16, into Sb) = AO8@Wo8^T * (1/16) + bo
    gemm_f8<<<dim3(8, 128, 1), 256, 0, stream>>>(
        Q8, 1024, 0, Wo8, 1024, 0, (void*)Sb, 1024, 0, bo, 1, 0.0625f, 0, 1024);
    // out = LN(pre + x)
    ln_res<<<16384, 256, 0, stream>>>((const bf16*)Sb, x, gamma, beta, out);
}